// Round 1
// 106.219 us; speedup vs baseline: 1.0554x; 1.0554x over previous
//
#include <hip/hip_runtime.h>

#define B_  8
#define S_  1024
#define E_  512
#define TI  64
#define TJ  64

typedef _Float16 half_t;
typedef _Float16 half2_t __attribute__((ext_vector_type(2)));
typedef _Float16 half8_t __attribute__((ext_vector_type(8)));
typedef float    floatx16 __attribute__((ext_vector_type(16)));
typedef unsigned int uint2v __attribute__((ext_vector_type(2)));
typedef unsigned int uint4v __attribute__((ext_vector_type(4)));

#define PHI_BYTES ((size_t)64 * S_ * 32 * 2)       // 64 bh x 1024 j x 32 halves = 4 MB
#define VT_BYTES  ((size_t)64 * 64 * S_ * 2)       // 64 bh x 64 d x 1024 j f16  = 8 MB

#define GLOAD_LDS16(g, l)                                                        \
    __builtin_amdgcn_global_load_lds((const __attribute__((address_space(1))) void*)(g), \
                                     (__attribute__((address_space(3))) void*)(l), 16, 0, 0)

// ---------------------------------------------------------------------------
// Pre-kernel: build Phi (rank-16 H/L feature maps, f16, MFMA per-lane order)
// and V^T (f16, [bh][d][j]) once. Kills all redundant trig in the main loop.
// grid (8 j-blocks, 64 bh) x 256
// ---------------------------------------------------------------------------
__global__ __launch_bounds__(256) void precompute_kernel(const float* __restrict__ x,
                                                         half_t* __restrict__ phi,
                                                         half_t* __restrict__ vt) {
    const int bh  = blockIdx.y;
    const int b   = bh >> 3, h = bh & 7;
    const int jb0 = blockIdx.x * 128;
    const int t   = threadIdx.x;
    __shared__ half_t tsh[128 * 65];

    // ---- Phi: thread = (j, sel); sel=0 -> wires 0-3 (L), sel=1 -> wires 4-7 (H)
    {
        const int jj = t >> 1, sel = t & 1;
        const int j  = jb0 + jj;
        const float* px = x + (size_t)b * S_ * E_ + (size_t)j * E_ + h * 64 + sel * 4;
        float4 w = *(const float4*)px;
        float xi[4] = {w.x, w.y, w.z, w.w};
        float c[4], s[4];
        #pragma unroll
        for (int q = 0; q < 4; ++q) {
            float v = xi[q] * 0.5f;
            c[q] = __cosf(v); s[q] = __sinf(v);
        }
        float pa[4] = {c[0]*c[1], s[0]*c[1], c[0]*s[1], s[0]*s[1]};
        float pb[4] = {c[2]*c[3], s[2]*c[3], c[2]*s[3], s[2]*s[3]};
        half_t f16[16];
        #pragma unroll
        for (int f = 0; f < 16; ++f)
            f16[f] = (half_t)(pa[f & 3] * pb[f >> 2]);   // identical math to make_frags
        // row layout: [H feat 0..15][L feat 0..15]  (64 B/row)
        half_t* dst = phi + ((size_t)bh * S_ + j) * 32 + (sel ? 0 : 16);
        *(half8_t*)dst       = *(half8_t*)&f16[0];
        *(half8_t*)(dst + 8) = *(half8_t*)&f16[8];
    }

    // ---- V^T: LDS transpose so global writes are coalesced
    {
        const float* xb = x + (size_t)b * S_ * E_ + h * 64;
        for (int k = 0; k < 32; ++k) {
            int idx = k * 256 + t;
            int j = idx >> 6, d = idx & 63;
            tsh[j * 65 + d] = (half_t)xb[(size_t)(jb0 + j) * E_ + d];
        }
        __syncthreads();
        for (int k = 0; k < 32; ++k) {
            int idx = k * 256 + t;
            int d = idx >> 7, j = idx & 127;
            vt[((size_t)bh * 64 + d) * S_ + jb0 + j] = tsh[j * 65 + d];
        }
    }
}

// ---------------------------------------------------------------------------
// Main kernel. grid (16 i-blocks, 64 bh) x 256 = 1024 blocks (4/CU).
// Wave wv = (ib, jb): i-band ib*32, j-band jb*32 of each 64-j chunk.
// Per chunk: S^T = 2 MFMAs (frags loaded from Phi), exp -> in-register
// PV A-frag via pack+permlane32_swap (no P LDS), V via global_load_lds,
// PV = 4 MFMAs. jb-partials reduced in LDS at the end.
// ---------------------------------------------------------------------------
__global__ __launch_bounds__(256, 4) void attn_kernel(const half_t* __restrict__ phi,
                                                      const half_t* __restrict__ vt,
                                                      float* __restrict__ out) {
    const int iblk = blockIdx.x;
    const int bh   = blockIdx.y;
    const int b    = bh >> 3, h = bh & 7;
    const int i0   = iblk * TI;
    const int t    = threadIdx.x;
    const int wv   = t >> 6, ln = t & 63;
    const int m    = ln & 31, hf = ln >> 5;
    const int ib   = wv >> 1, jb = wv & 1;

    __shared__ __align__(16) half_t sh_v[8 * 64 * 8];   // [jq(8)][d(64)] x 8 halves, 8 KB
    __shared__ float sh_red[2][32][64];                  // jb=1 partial O, 16 KB
    __shared__ float sh_den[2][64];

    const half_t* phb = phi + (size_t)bh * S_ * 32;

    // B-side fragments Phi_i (from precomputed table — no trig)
    half8_t biH, biL;
    {
        const half_t* pr = phb + (size_t)(i0 + ib * 32 + m) * 32 + hf * 8;
        biH = *(const half8_t*)pr;
        biL = *(const half8_t*)(pr + 16);
    }

    floatx16 acc0, acc1, z;
    #pragma unroll
    for (int k = 0; k < 16; ++k) { acc0[k] = 0.f; acc1[k] = 0.f; z[k] = 0.f; }
    float d0 = 0.f, d1 = 0.f;

    // staging: lane ln owns V^T row d=ln; wave wv stages jq = 2wv, 2wv+1
    const half_t* vsrc = vt + ((size_t)bh * 64 + ln) * S_;
    const half_t* asrc = phb + (size_t)(jb * 32 + m) * 32 + hf * 8;

    for (int j0 = 0; j0 < S_; j0 += TJ) {
        __syncthreads();   // previous chunk's V reads done before restage

        // async V stage: LDS dest is lane-linear (slot*16B), global src per-lane
        GLOAD_LDS16(vsrc + j0 + (2 * wv + 0) * 8, &sh_v[(2 * wv + 0) * 64 * 8]);
        GLOAD_LDS16(vsrc + j0 + (2 * wv + 1) * 8, &sh_v[(2 * wv + 1) * 64 * 8]);

        // A-side fragments Phi_j (L2-resident loads, no trig)
        const half_t* ar = asrc + (size_t)j0 * 32;
        half8_t ajH = *(const half8_t*)ar;
        half8_t ajL = *(const half8_t*)(ar + 16);

        // S^T[j][i]: lane holds j=(r&3)+8*(r>>2)+4*hf (own tile), i=m (own band)
        floatx16 sH = __builtin_amdgcn_mfma_f32_32x32x16_f16(ajH, biH, z, 0, 0, 0);
        floatx16 sL = __builtin_amdgcn_mfma_f32_32x32x16_f16(ajL, biL, z, 0, 0, 0);

        // P = exp|sH*sL|, packed to f16 pairs entirely in registers
        unsigned int dwa[4], dwb[4];
        #pragma unroll
        for (int g = 0; g < 4; ++g) {
            float p[4];
            #pragma unroll
            for (int r = 0; r < 4; ++r) {
                float sc = sH[4 * g + r] * sL[4 * g + r];
                p[r] = __expf(__builtin_fabsf(sc));
            }
            d0 += p[0] + p[2];
            d1 += p[1] + p[3];
            half2_t ha = {(half_t)p[0], (half_t)p[1]};
            half2_t hb = {(half_t)p[2], (half_t)p[3]};
            dwa[g] = __builtin_bit_cast(unsigned int, ha);
            dwb[g] = __builtin_bit_cast(unsigned int, hb);
        }
        // hf-half exchange: lane(m,hf) ends with P[i=m][j = hf*8+e (ap0), 16+hf*8+e (ap1)]
        uint2v swA0 = __builtin_amdgcn_permlane32_swap(dwa[0], dwa[1], false, false);
        uint2v swB0 = __builtin_amdgcn_permlane32_swap(dwb[0], dwb[1], false, false);
        uint2v swA1 = __builtin_amdgcn_permlane32_swap(dwa[2], dwa[3], false, false);
        uint2v swB1 = __builtin_amdgcn_permlane32_swap(dwb[2], dwb[3], false, false);
        half8_t ap0 = __builtin_bit_cast(half8_t, (uint4v){swA0.x, swB0.x, swA0.y, swB0.y});
        half8_t ap1 = __builtin_bit_cast(half8_t, (uint4v){swA1.x, swB1.x, swA1.y, swB1.y});

        __syncthreads();   // drains vmcnt(0): sh_v ready

        // B-frags: contiguous 16B slots across lanes -> conflict-free ds_read_b128
        const int q0 = jb * 4;
        half8_t b00 = *(const half8_t*)&sh_v[(((q0 + 0 + hf) * 64) + m) * 8];
        half8_t b01 = *(const half8_t*)&sh_v[(((q0 + 2 + hf) * 64) + m) * 8];
        half8_t b10 = *(const half8_t*)&sh_v[(((q0 + 0 + hf) * 64) + 32 + m) * 8];
        half8_t b11 = *(const half8_t*)&sh_v[(((q0 + 2 + hf) * 64) + 32 + m) * 8];

        acc0 = __builtin_amdgcn_mfma_f32_32x32x16_f16(ap0, b00, acc0, 0, 0, 0);
        acc0 = __builtin_amdgcn_mfma_f32_32x32x16_f16(ap1, b01, acc0, 0, 0, 0);
        acc1 = __builtin_amdgcn_mfma_f32_32x32x16_f16(ap0, b10, acc1, 0, 0, 0);
        acc1 = __builtin_amdgcn_mfma_f32_32x32x16_f16(ap1, b11, acc1, 0, 0, 0);
    }

    // ---- epilogue: combine hf halves of denominator, then jb partials of O
    float dtot = d0 + d1;
    dtot += __shfl_xor(dtot, 32, 64);
    sh_den[jb][ib * 32 + m] = dtot;
    if (jb == 1) {
        #pragma unroll
        for (int reg = 0; reg < 16; ++reg) {
            int il = (reg & 3) + 8 * (reg >> 2) + 4 * hf;
            sh_red[ib][il][m]      = acc0[reg];
            sh_red[ib][il][32 + m] = acc1[reg];
        }
    }
    __syncthreads();
    if (jb == 0) {
        #pragma unroll
        for (int reg = 0; reg < 16; ++reg) {
            int il = (reg & 3) + 8 * (reg >> 2) + 4 * hf;
            float inv = 1.f / (sh_den[0][ib * 32 + il] + sh_den[1][ib * 32 + il]);
            size_t base = ((size_t)(b * S_ + i0 + ib * 32 + il)) * E_ + h * 64 + m;
            out[base]      = (acc0[reg] + sh_red[ib][il][m])      * inv;
            out[base + 32] = (acc1[reg] + sh_red[ib][il][32 + m]) * inv;
        }
    }
}

extern "C" void kernel_launch(void* const* d_in, const int* in_sizes, int n_in,
                              void* d_out, int out_size, void* d_ws, size_t ws_size,
                              hipStream_t stream) {
    const float* x = (const float*)d_in[0];
    float* out = (float*)d_out;
    half_t* phi = (half_t*)d_ws;
    half_t* vt  = (half_t*)((char*)d_ws + PHI_BYTES);
    precompute_kernel<<<dim3(8, 64), 256, 0, stream>>>(x, phi, vt);
    attn_kernel<<<dim3(S_ / TI, 64), 256, 0, stream>>>(phi, vt, out);
}